// Round 1
// 416.968 us; speedup vs baseline: 1.0005x; 1.0005x over previous
//
#include <hip/hip_runtime.h>

// Problem constants
// B=16, N=32, D_OBS=128, N_ACT=16, D_OA_IN=144, D=128, HID=64
// noise: [16,32,32,32,128] f32 = 256 MiB  -> the HBM-bound part.

// workspace layout (float offsets)
#define WS_K    0         // [512][128]
#define WS_Q    65536
#define WS_VA   131072
#define WS_KO   196608
#define WS_QO   262144
#define WS_AVO  327680
#define WS_SDIV 393216    // S/32            [512][128]
#define WS_DDIV 458752    // (Vp-Va)/32      [512][128]
#define WS_U    524288    // u = W1a@wfo     [512][64]
#define WS_WOA  557056    // copy of w_oa    [512][32]
// end: 573440 floats = 2.3 MB

// ---------------------------------------------------------------------------
// Kernel 1: per-row linear transforms.  grid = 512 (b*32+i), block = 256.
// ---------------------------------------------------------------------------
__global__ __launch_bounds__(256) void k_transforms(
    const float* __restrict__ states, const float* __restrict__ policies,
    const float* __restrict__ actions,
    const float* __restrict__ Wk_oa, const float* __restrict__ Wq_oa,
    const float* __restrict__ Wv_oa, const float* __restrict__ Wk_o,
    const float* __restrict__ Wq_o,  const float* __restrict__ Wv_o,
    float* __restrict__ ws)
{
    __shared__ __align__(16) float xa[144];   // obs_actions row
    const int row = blockIdx.x;               // b*32 + i
    const int t = threadIdx.x;
    if (t < 128)       xa[t] = states[row * 128 + t];
    else if (t < 144)  xa[t] = actions[row * 16 + (t - 128)];
    __syncthreads();

    for (int u = t; u < 768; u += 256) {
        const int m = u >> 7, o = u & 127;
        const float* Wrow; int len4; float* dst;
        switch (m) {
            case 0: Wrow = Wk_oa + o * 144; len4 = 36; dst = ws + WS_K;  break;
            case 1: Wrow = Wq_oa + o * 144; len4 = 36; dst = ws + WS_Q;  break;
            case 2: Wrow = Wv_oa + o * 144; len4 = 36; dst = ws + WS_VA; break;
            case 3: Wrow = Wk_o  + o * 128; len4 = 32; dst = ws + WS_KO; break;
            case 4: Wrow = Wq_o  + o * 128; len4 = 32; dst = ws + WS_QO; break;
            default:Wrow = Wv_o  + o * 128; len4 = 32; dst = ws + WS_AVO;break;
        }
        const float4* W4 = (const float4*)Wrow;
        const float4* x4 = (const float4*)xa;
        float acc = 0.f;
        for (int c = 0; c < len4; ++c) {
            float4 w = W4[c], x = x4[c];
            acc += w.x * x.x + w.y * x.y + w.z * x.z + w.w * x.w;
        }
        dst[row * 128 + o] = acc;
    }
}

// ---------------------------------------------------------------------------
// Kernel 2: attention rows.  grid = 512 (b*32+r), block = 256.
// Also zeroes out[0:16384] so k_value can accumulate with atomics.
// ---------------------------------------------------------------------------
__global__ __launch_bounds__(256) void k_attn(
    const float* __restrict__ policies, const float* __restrict__ actions,
    const float* __restrict__ Wv_oa, const float* __restrict__ W1,
    float* __restrict__ ws, float* __restrict__ out)
{
    const float* K   = ws + WS_K;
    const float* Q   = ws + WS_Q;
    const float* Va  = ws + WS_VA;
    const float* Ko  = ws + WS_KO;
    const float* Qo  = ws + WS_QO;
    const float* AVO = ws + WS_AVO;
    float* Sdiv = ws + WS_SDIV;
    float* Ddiv = ws + WS_DDIV;
    float* U    = ws + WS_U;
    float* Woa  = ws + WS_WOA;

    const int b = blockIdx.x >> 5, r = blockIdx.x & 31;
    const int t = threadIdx.x;
    const int br = b * 32 + r;

    __shared__ __align__(16) float kr[128], kor[128], wfo[128];
    __shared__ float sA[32], sO[32], woa[32], wo[32], pd[16];

    if (t < 32) out[br * 32 + t] = 0.f;   // zero value region for k_value atomics
    if (t < 128) { kr[t] = K[br * 128 + t]; kor[t] = Ko[br * 128 + t]; }
    else if (t < 144) {
        int c = t - 128;
        pd[c] = policies[br * 16 + c] - actions[br * 16 + c];
    }
    __syncthreads();

    // scores: i = t>>3 (8 lanes per dot, 16 floats each)
    {
        const int i = t >> 3, seg = t & 7;
        const float4* q4  = (const float4*)(Q  + (b * 32 + i) * 128) + seg * 4;
        const float4* qo4 = (const float4*)(Qo + (b * 32 + i) * 128) + seg * 4;
        const float4* k4  = (const float4*)kr  + seg * 4;
        const float4* ko4 = (const float4*)kor + seg * 4;
        float a0 = 0.f, a1 = 0.f;
        #pragma unroll
        for (int c = 0; c < 4; ++c) {
            float4 q = q4[c], kk = k4[c];
            a0 += q.x * kk.x + q.y * kk.y + q.z * kk.z + q.w * kk.w;
            float4 p = qo4[c], mm = ko4[c];
            a1 += p.x * mm.x + p.y * mm.y + p.z * mm.z + p.w * mm.w;
        }
        #pragma unroll
        for (int off = 1; off < 8; off <<= 1) {
            a0 += __shfl_xor(a0, off, 64);
            a1 += __shfl_xor(a1, off, 64);
        }
        if (seg == 0) {
            const float scale = 0.08838834764831845f;  // 1/sqrt(128)
            sA[i] = a0 * scale;
            sO[i] = a1 * scale;
        }
    }
    __syncthreads();

    // softmax over 32, lanes 0..31 do w_oa, lanes 32..63 do w_o
    if (t < 64) {
        const int i = t & 31;
        float s = (t < 32) ? sA[i] : sO[i];
        float m = s;
        #pragma unroll
        for (int off = 1; off < 32; off <<= 1) m = fmaxf(m, __shfl_xor(m, off, 64));
        float e = __expf(s - m);
        float sum = e;
        #pragma unroll
        for (int off = 1; off < 32; off <<= 1) sum += __shfl_xor(sum, off, 64);
        float w = e / sum;
        if (t < 32) { woa[i] = w; out[16384 + br * 32 + i] = w; Woa[br * 32 + i] = w; }
        else        { wo[i]  = w; out[32768 + br * 32 + i] = w; }
    }
    __syncthreads();

    // S/32 (t<128), wfo (t>=128), diff*Wv/32 (t<128)
    {
        const int d = t & 127;
        const float* M  = (t < 128) ? Va  : AVO;
        const float* wp = (t < 128) ? woa : wo;
        float acc = 0.f;
        #pragma unroll 8
        for (int i = 0; i < 32; ++i) acc += wp[i] * M[(b * 32 + i) * 128 + d];
        if (t < 128) {
            Sdiv[br * 128 + d] = acc * (1.f / 32.f);
            const float4* wv4 = (const float4*)(Wv_oa + d * 144 + 128);
            float dv = 0.f;
            #pragma unroll
            for (int c = 0; c < 4; ++c) {
                float4 w = wv4[c];
                dv += w.x * pd[4*c] + w.y * pd[4*c+1] + w.z * pd[4*c+2] + w.w * pd[4*c+3];
            }
            Ddiv[br * 128 + d] = dv * (1.f / 32.f);
        } else {
            wfo[d] = acc * (1.f / 32.f);
        }
    }
    __syncthreads();

    // u[h] = W1[h, 0:128] . wfo   (4 lanes per h)
    {
        const int h = t >> 2, qq = t & 3;
        const float4* w4 = (const float4*)(W1 + h * 256) + qq * 8;
        const float4* f4 = (const float4*)wfo + qq * 8;
        float acc = 0.f;
        #pragma unroll
        for (int c = 0; c < 8; ++c) {
            float4 w = w4[c], f = f4[c];
            acc += w.x * f.x + w.y * f.y + w.z * f.z + w.w * f.w;
        }
        acc += __shfl_xor(acc, 1, 64);
        acc += __shfl_xor(acc, 2, 64);
        if (qq == 0) U[br * 64 + h] = acc;
    }
}

// ---------------------------------------------------------------------------
// Kernel 3: the HBM-bound one.  grid = 1024 ((b,k,j-half)), block = 256.
// Restructured: per-wave i-reduction (no cross-wave LDS), ONE raw s_barrier
// per j-iteration with lgkmcnt-only wait (noise prefetch stays in flight),
// double-buffered wav, Ddiv staged in LDS, atomicAdd final (out pre-zeroed).
// ---------------------------------------------------------------------------
__global__ __launch_bounds__(256) void k_value(
    const float* __restrict__ noise, const float* __restrict__ ws,
    const float* __restrict__ W1, const float* __restrict__ W2,
    float* __restrict__ out)
{
    const float* Sdiv = ws + WS_SDIV;
    const float* Ddiv = ws + WS_DDIV;
    const float* U    = ws + WS_U;
    const float* Woa  = ws + WS_WOA;

    const int blk = blockIdx.x;
    const int b  = blk >> 6;
    const int k  = (blk >> 1) & 31;
    const int j0 = (blk & 1) * 16;
    const int t  = threadIdx.x;
    const int l  = t & 63, wv = t >> 6;
    const int h  = t >> 2, q = t & 3;
    const int bk = b * 32 + k;

    __shared__ __align__(16) float wavs[2][4][36];   // double-buffered, 36-pad
    __shared__ __align__(16) float sdiv_s[128];
    __shared__ __align__(16) float ddiv_s[16 * 128]; // this block's 16 Ddiv rows
    __shared__ float woa_s[16];

    // per-thread constants: W1b chunk (h, d in [q*32, q*32+32)), u, w2
    float w1r[32];
    {
        const float4* p = (const float4*)(W1 + h * 256 + 128 + q * 32);
        #pragma unroll
        for (int c = 0; c < 8; ++c) {
            float4 v = p[c];
            w1r[4*c] = v.x; w1r[4*c+1] = v.y; w1r[4*c+2] = v.z; w1r[4*c+3] = v.w;
        }
    }
    const float u_h  = U[bk * 64 + h];
    const float w2_h = W2[h];

    if (t < 32) ((float4*)sdiv_s)[t] = ((const float4*)(Sdiv + bk * 128))[t];
    {
        const float4* dsrc = (const float4*)(Ddiv + (b * 32 + j0) * 128);
        ((float4*)ddiv_s)[t]       = dsrc[t];
        ((float4*)ddiv_s)[t + 256] = dsrc[t + 256];
    }
    if (t < 16) woa_s[t] = Woa[bk * 32 + j0 + t];
    __syncthreads();   // one full barrier; everything after uses raw s_barrier

    // wave wv owns d-slice [wv*32, wv*32+32): lane covers float4-col d4,
    // i = i0 + {0,8,16,24}. Full i-sum completed in-wave via shfl_xor.
    const int d4 = (wv << 3) + (l & 7);
    const int i0 = l >> 3;
    const float4* nb = (const float4*)noise + (size_t)bk * 32768 + (size_t)(i0 * 32 + d4);

    float4 n0, n1, n2, n3;
    {
        const float4* p = nb + (size_t)j0 * 1024;
        n0 = p[0]; n1 = p[256]; n2 = p[512]; n3 = p[768];
    }
    #pragma unroll 2
    for (int jj = 0; jj < 16; ++jj) {
        const int j = j0 + jj;
        float4 m0{}, m1{}, m2{}, m3{};
        if (jj < 15) {
            const float4* p = nb + (size_t)(j + 1) * 1024;
            m0 = p[0]; m1 = p[256]; m2 = p[512]; m3 = p[768];
        }
        // i-partials over this lane's 4 i's, then reduce over the 8 i-groups
        float sx = n0.x + n1.x + n2.x + n3.x;
        float sy = n0.y + n1.y + n2.y + n3.y;
        float sz = n0.z + n1.z + n2.z + n3.z;
        float sw = n0.w + n1.w + n2.w + n3.w;
        #pragma unroll
        for (int off = 8; off < 64; off <<= 1) {
            sx += __shfl_xor(sx, off, 64);
            sy += __shfl_xor(sy, off, 64);
            sz += __shfl_xor(sz, off, 64);
            sw += __shfl_xor(sw, off, 64);
        }
        const float woaj = woa_s[jj];
        if (l < 8) {
            const int db = (wv << 5) + (l << 2);
            float4 w;
            w.x = sdiv_s[db+0] + ddiv_s[jj*128+db+0] * woaj + sx * (0.1f/32.f) - 0.05f;
            w.y = sdiv_s[db+1] + ddiv_s[jj*128+db+1] * woaj + sy * (0.1f/32.f) - 0.05f;
            w.z = sdiv_s[db+2] + ddiv_s[jj*128+db+2] * woaj + sz * (0.1f/32.f) - 0.05f;
            w.w = sdiv_s[db+3] + ddiv_s[jj*128+db+3] * woaj + sw * (0.1f/32.f) - 0.05f;
            *(float4*)&wavs[jj & 1][wv][l << 2] = w;
        }
        // lgkm-only wait: noise prefetch (vmcnt) stays in flight across barrier
        asm volatile("s_waitcnt lgkmcnt(0)" ::: "memory");
        __builtin_amdgcn_s_barrier();
        __builtin_amdgcn_sched_barrier(0);
        // h[h] = u_h + W1b[h,:] . wav ; leaky ; dot W2 ; per-wave atomic
        {
            const float4* w4 = (const float4*)&wavs[jj & 1][q][0];
            float acc = 0.f;
            #pragma unroll
            for (int c = 0; c < 8; ++c) {
                float4 v = w4[c];
                acc += w1r[4*c] * v.x + w1r[4*c+1] * v.y
                     + w1r[4*c+2] * v.z + w1r[4*c+3] * v.w;
            }
            acc += __shfl_xor(acc, 1, 64);
            acc += __shfl_xor(acc, 2, 64);
            float vp = 0.f;
            if (q == 0) {
                float hv = u_h + acc;
                hv = (hv > 0.f) ? hv : 0.01f * hv;
                vp = hv * w2_h;
            }
            #pragma unroll
            for (int off = 4; off < 64; off <<= 1) vp += __shfl_xor(vp, off, 64);
            if (l == 0) atomicAdd(out + bk * 32 + j, vp);
        }
        n0 = m0; n1 = m1; n2 = m2; n3 = m3;
    }
}

extern "C" void kernel_launch(void* const* d_in, const int* in_sizes, int n_in,
                              void* d_out, int out_size, void* d_ws, size_t ws_size,
                              hipStream_t stream) {
    const float* states   = (const float*)d_in[0];
    const float* policies = (const float*)d_in[1];
    const float* actions  = (const float*)d_in[2];
    const float* noise    = (const float*)d_in[3];
    const float* Wk_oa    = (const float*)d_in[4];
    const float* Wq_oa    = (const float*)d_in[5];
    const float* Wv_oa    = (const float*)d_in[6];
    const float* Wk_o     = (const float*)d_in[7];
    const float* Wq_o     = (const float*)d_in[8];
    const float* Wv_o     = (const float*)d_in[9];
    const float* W1       = (const float*)d_in[10];
    const float* W2       = (const float*)d_in[11];
    float* out = (float*)d_out;
    float* ws  = (float*)d_ws;

    k_transforms<<<512, 256, 0, stream>>>(states, policies, actions,
                                          Wk_oa, Wq_oa, Wv_oa, Wk_o, Wq_o, Wv_o, ws);
    k_attn<<<512, 256, 0, stream>>>(policies, actions, Wv_oa, W1, ws, out);
    k_value<<<1024, 256, 0, stream>>>(noise, ws, W1, W2, out);
}